// Round 3
// baseline (137.018 us; speedup 1.0000x reference)
//
#include <hip/hip_runtime.h>
#include <hip/hip_bf16.h>
#include <math.h>
#include <stddef.h>

// Problem shape: z [4,64,16,32,32] fp32, embedding [1024,64] fp32
#define CH     64
#define DHWC   16384
#define NTOK   65536
#define KCODES 1024
#define OUT_ELEMS 4194304

typedef _Float16 f16;
typedef f16  f16x8  __attribute__((ext_vector_type(8)));
typedef float fltx4 __attribute__((ext_vector_type(4)));

struct Ws {
  // ---- zeroed header (memset range = offsetof(Ws, e_norm)) ----
  double sum_z2, sum_e2, loss_sum, pad;
  float  sum_z[CH];               // native f32 atomics from gemm h==0 blocks
  double sum_e[CH];
  int    counts[KCODES];
  // ---- filled by eprep ----
  float  e_norm[KCODES];
  float  accI[KCODES + 48];       // -e_norm/2; +48 pad for depth-2 prefetch
  // codebook pre-swizzled into MFMA B-fragment order (verified):
  // +2 pad rows for depth-2 prefetch overrun (values loaded, never used)
  f16    e_frag[(64 + 2) * 2 * 64 * 8];
  // ---- per-half exact winners (gemm -> writer) ----
  float          hd[2 * NTOK];
  unsigned short hk[2 * NTOK];
};

// ---- eprep: e_norm (exact chain) + channel sums + sum_e2 + fragments ----
__global__ void vq_eprep(const float* __restrict__ emb, Ws* __restrict__ ws) {
  __shared__ float tile[64][68];
  __shared__ float red[256];
  const int tid = threadIdx.x;
  const int r = tid >> 2;                 // code row within block (0..63)
  const int q = tid & 3;                  // quarter of the 64-channel row
  const int k = blockIdx.x * 64 + r;
  const float4* src = (const float4*)(emb + (size_t)k * CH + q * 16);
  float4 a = src[0], b = src[1], c = src[2], d = src[3];
  float4* dst = (float4*)(&tile[r][q * 16]);
  dst[0] = a; dst[1] = b; dst[2] = c; dst[3] = d;
  float s2 = 0.f;
  s2 = fmaf(a.x,a.x,s2); s2 = fmaf(a.y,a.y,s2); s2 = fmaf(a.z,a.z,s2); s2 = fmaf(a.w,a.w,s2);
  s2 = fmaf(b.x,b.x,s2); s2 = fmaf(b.y,b.y,s2); s2 = fmaf(b.z,b.z,s2); s2 = fmaf(b.w,b.w,s2);
  s2 = fmaf(c.x,c.x,s2); s2 = fmaf(c.y,c.y,s2); s2 = fmaf(c.z,c.z,s2); s2 = fmaf(c.w,c.w,s2);
  s2 = fmaf(d.x,d.x,s2); s2 = fmaf(d.y,d.y,s2); s2 = fmaf(d.z,d.z,s2); s2 = fmaf(d.w,d.w,s2);
  // verified-exact row norm (absmax 0.0)
  float t1 = s2 + __shfl_xor(s2, 1);
  float t2 = t1 + __shfl_xor(t1, 2);
  if (q == 0) { ws->e_norm[k] = t2; ws->accI[k] = -0.5f * t2; }
  // pre-swizzled B-fragment write (verified)
  {
    float vals[16] = {a.x,a.y,a.z,a.w, b.x,b.y,b.z,b.w,
                      c.x,c.y,c.z,c.w, d.x,d.y,d.z,d.w};
    const int ct  = blockIdx.x * 4 + (r >> 4);
    const int nn  = r & 15;
    const int b01 = q >> 1;
    const int qd0 = (q & 1) * 2;
    f16 h8a[8], h8b[8];
    #pragma unroll
    for (int u = 0; u < 8; ++u) { h8a[u] = (f16)vals[u]; h8b[u] = (f16)vals[8 + u]; }
    f16x8* fr = (f16x8*)ws->e_frag;
    fr[(ct * 2 + b01) * 64 + (qd0 + 0) * 16 + nn] = *(f16x8*)h8a;
    fr[(ct * 2 + b01) * 64 + (qd0 + 1) * 16 + nn] = *(f16x8*)h8b;
  }
  red[tid] = s2;
  __syncthreads();
  for (int off = 128; off > 0; off >>= 1) {
    if (tid < off) red[tid] += red[tid + off];
    __syncthreads();
  }
  if (tid == 0) atomicAdd(&ws->sum_e2, (double)red[0]);
  if (tid < CH) {
    float cs = 0.f;
    #pragma unroll 8
    for (int rr = 0; rr < 64; ++rr) cs += tile[rr][tid];
    atomicAdd(&ws->sum_e[tid], (double)cs);
  }
}

// ---- phase 1+2: MFMA candidates + exact per-half recheck ----------------
// R3: 64 tokens per WAVE (256/block): per iter 2 B-loads + 1 accI feed
// 8 MFMAs (was 4) -> load latency hidden by compute. Top-2 per class with
// packed keys (key = (score & ~1023) | (1023-k)): 4 VALU/value, restores
// the verified two-blocker candidate robustness. grid 512 = 256 tg x 2 h.
__global__ __launch_bounds__(256, 2)
void vq_gemm(const float* __restrict__ z, const float* __restrict__ emb,
             Ws* __restrict__ ws) {
  // LDS: [0,36864) zh f16[256][72], reused as cand f32[256][36]
  //      [36864,38912) shs f32[512] (staging sums)
  __shared__ char smem[38912];
  f16*   zh   = (f16*)smem;
  float* cand = (float*)smem;
  float* shs  = (float*)(smem + 36864);

  const int tid = threadIdx.x;
  const int h   = blockIdx.x & 1;          // K-half
  const int tg  = blockIdx.x >> 1;         // token group (256 tokens)
  const int n0  = tg * 256;
  const int b   = n0 >> 14;
  const int s0  = n0 & 16383;
  const float* zbase = z + (size_t)b * (CH * DHWC) + s0;

  // stage z -> f16 [token][c] (stride 72); h==0 blocks also do channel sums
  {
    const int c = tid >> 2;            // 0..63
    const int q = tid & 3;             // token quarter (64 tokens)
    const float4* src = (const float4*)(zbase + (size_t)c * DHWC) + q * 16;
    float ss = 0.f, ss2 = 0.f;
    #pragma unroll
    for (int i = 0; i < 16; ++i) {
      float4 v = src[i];
      const int t0 = q * 64 + i * 4;
      zh[(t0 + 0) * 72 + c] = (f16)v.x;
      zh[(t0 + 1) * 72 + c] = (f16)v.y;
      zh[(t0 + 2) * 72 + c] = (f16)v.z;
      zh[(t0 + 3) * 72 + c] = (f16)v.w;
      ss += v.x + v.y + v.z + v.w;
      ss2 = fmaf(v.x, v.x, ss2); ss2 = fmaf(v.y, v.y, ss2);
      ss2 = fmaf(v.z, v.z, ss2); ss2 = fmaf(v.w, v.w, ss2);
    }
    shs[tid] = ss; shs[256 + tid] = ss2;
  }
  __syncthreads();
  if (h == 0 && tid < 64) {
    float cs = shs[4*tid] + shs[4*tid+1] + shs[4*tid+2] + shs[4*tid+3];
    atomicAdd(&ws->sum_z[tid], cs);
    float cs2 = shs[256+4*tid] + shs[256+4*tid+1] + shs[256+4*tid+2] + shs[256+4*tid+3];
    #pragma unroll
    for (int off = 32; off > 0; off >>= 1) cs2 += __shfl_down(cs2, off);
    if (tid == 0) atomicAdd(&ws->sum_z2, (double)cs2);
  }

  const int lane = tid & 63;
  const int w    = tid >> 6;           // wave: tokens [w*64, w*64+64)
  const int nn   = lane & 15;          // MFMA column (code class)
  const int quad = lane >> 4;

  // A fragments (verified layout): A[m=lane&15][k=quad*8+j], 4 M-tiles
  f16x8 Ah[4][2];
  #pragma unroll
  for (int mt = 0; mt < 4; ++mt) {
    const int row = w * 64 + mt * 16 + nn;
    #pragma unroll
    for (int ks = 0; ks < 2; ++ks)
      Ah[mt][ks] = *(const f16x8*)(&zh[row * 72 + ks * 32 + quad * 8]);
  }

  // packed-key top-2 per (token-slot, class):
  // key = (score bits & ~1023) | (1023 - k): distinct keys, max = best,
  // k decodable from low 10 bits; exact distances restored by recheck.
  float m1[16], m2[16];
  #pragma unroll
  for (int u = 0; u < 16; ++u) { m1[u] = -3.4e38f; m2[u] = -3.4e38f; }

  const f16x8* __restrict__ fr  = ((const f16x8*)ws->e_frag) + lane;
  const float* __restrict__ aIp = ws->accI;

  int ct = h * 32;
  f16x8 B0a = fr[(ct * 2 + 0) * 64];
  f16x8 B1a = fr[(ct * 2 + 1) * 64];
  f16x8 B0b = fr[(ct * 2 + 2) * 64];
  f16x8 B1b = fr[(ct * 2 + 3) * 64];
  float aia = aIp[ct * 16 + nn];
  float aib = aIp[ct * 16 + 16 + nn];
  unsigned orb = (unsigned)(1023 - ct * 16 - nn);
  #pragma unroll 2
  for (int it = 0; it < 32; ++it) {
    const int pct = ct + 2;            // depth-2 prefetch (pad rows at end)
    f16x8 nB0 = fr[(pct * 2 + 0) * 64];
    f16x8 nB1 = fr[(pct * 2 + 1) * 64];
    const float nai = aIp[pct * 16 + nn];
    fltx4 acc[4];
    #pragma unroll
    for (int mt = 0; mt < 4; ++mt) {
      fltx4 a = {aia, aia, aia, aia};
      a = __builtin_amdgcn_mfma_f32_16x16x32_f16(Ah[mt][0], B0a, a, 0, 0, 0);
      a = __builtin_amdgcn_mfma_f32_16x16x32_f16(Ah[mt][1], B1a, a, 0, 0, 0);
      acc[mt] = a;
    }
    #pragma unroll
    for (int mt = 0; mt < 4; ++mt)
      #pragma unroll
      for (int r = 0; r < 4; ++r) {
        const int u = mt * 4 + r;
        unsigned tb = (__float_as_uint(acc[mt][r]) & 0xFFFFFC00u) | orb;
        float key = __uint_as_float(tb);
        m2[u] = fmaxf(m2[u], fminf(m1[u], key));
        m1[u] = fmaxf(m1[u], key);
      }
    orb -= 16;
    ++ct;
    B0a = B0b; B1a = B1b; aia = aib;
    B0b = nB0; B1b = nB1; aib = nai;
  }

  __syncthreads();          // zh reads done; safe to overwrite as cand
  // 32 class winners per token; stride 36 floats (16B-aligned rows)
  #pragma unroll
  for (int mt = 0; mt < 4; ++mt)
    #pragma unroll
    for (int r = 0; r < 4; ++r) {
      const int tok = w * 64 + mt * 16 + quad * 4 + r;  // C/D row (verified)
      cand[tok * 36 + nn]      = m1[mt * 4 + r];
      cand[tok * 36 + 16 + nn] = m2[mt * 4 + r];
    }
  __syncthreads();

  // thread == token: top-4 of 32 keys, then exact recheck of 4 candidates
  float bv[4] = {-3.4e38f, -3.4e38f, -3.4e38f, -3.4e38f};
  {
    const float4* cp = (const float4*)(cand + tid * 36);
    #pragma unroll
    for (int i4 = 0; i4 < 8; ++i4) {
      float4 v = cp[i4];
      float av[4] = {v.x, v.y, v.z, v.w};
      #pragma unroll
      for (int e = 0; e < 4; ++e) {
        float a = av[e];
        #pragma unroll
        for (int j = 0; j < 4; ++j) {
          bool ins = a > bv[j];
          float t = bv[j];
          bv[j] = ins ? a : bv[j];
          a = ins ? t : a;
        }
      }
    }
  }
  {
    const int k0 = 1023 - (int)(__float_as_uint(bv[0]) & 1023u);
    const int k1 = 1023 - (int)(__float_as_uint(bv[1]) & 1023u);
    const int k2 = 1023 - (int)(__float_as_uint(bv[2]) & 1023u);
    const int k3 = 1023 - (int)(__float_as_uint(bv[3]) & 1023u);
    const float4* e0p = (const float4*)(emb + (size_t)k0 * CH);
    const float4* e1p = (const float4*)(emb + (size_t)k1 * CH);
    const float4* e2p = (const float4*)(emb + (size_t)k2 * CH);
    const float4* e3p = (const float4*)(emb + (size_t)k3 * CH);
    const float* zt = zbase + tid;
    float znorm = 0.f, d0 = 0.f, d1 = 0.f, d2 = 0.f, d3 = 0.f;
    #pragma unroll 4
    for (int c4 = 0; c4 < 16; ++c4) {
      float4 ev0 = e0p[c4];
      float4 ev1 = e1p[c4];
      float4 ev2 = e2p[c4];
      float4 ev3 = e3p[c4];
      float v0 = zt[(size_t)(4*c4+0) * DHWC];
      float v1 = zt[(size_t)(4*c4+1) * DHWC];
      float v2 = zt[(size_t)(4*c4+2) * DHWC];
      float v3 = zt[(size_t)(4*c4+3) * DHWC];
      znorm = fmaf(v0, v0, znorm); znorm = fmaf(v1, v1, znorm);
      znorm = fmaf(v2, v2, znorm); znorm = fmaf(v3, v3, znorm);
      d0 = fmaf(v0, ev0.x, d0); d0 = fmaf(v1, ev0.y, d0);
      d0 = fmaf(v2, ev0.z, d0); d0 = fmaf(v3, ev0.w, d0);
      d1 = fmaf(v0, ev1.x, d1); d1 = fmaf(v1, ev1.y, d1);
      d1 = fmaf(v2, ev1.z, d1); d1 = fmaf(v3, ev1.w, d1);
      d2 = fmaf(v0, ev2.x, d2); d2 = fmaf(v1, ev2.y, d2);
      d2 = fmaf(v2, ev2.z, d2); d2 = fmaf(v3, ev2.w, d2);
      d3 = fmaf(v0, ev3.x, d3); d3 = fmaf(v1, ev3.y, d3);
      d3 = fmaf(v2, ev3.z, d3); d3 = fmaf(v3, ev3.w, d3);
    }
    float dd0 = fmaf(-2.f, d0, znorm + ws->e_norm[k0]);
    float dd1 = fmaf(-2.f, d1, znorm + ws->e_norm[k1]);
    float dd2 = fmaf(-2.f, d2, znorm + ws->e_norm[k2]);
    float dd3 = fmaf(-2.f, d3, znorm + ws->e_norm[k3]);
    float dd = dd0; int kk = k0;
    if (dd1 < dd || (dd1 == dd && k1 < kk)) { dd = dd1; kk = k1; }
    if (dd2 < dd || (dd2 == dd && k2 < kk)) { dd = dd2; kk = k2; }
    if (dd3 < dd || (dd3 == dd && k3 < kk)) { dd = dd3; kk = k3; }
    ws->hd[h * NTOK + n0 + tid] = dd;
    ws->hk[h * NTOK + n0 + tid] = (unsigned short)kk;
  }
}

// ---- phase 3: combine halves + output + loss + counts --------------------
// grid 256 x 1024; block = ONE (b,c) plane (verified ~11 us)
__global__ __launch_bounds__(1024, 4)
void vq_writer(const float* __restrict__ z, const float* __restrict__ emb,
               float* __restrict__ out, Ws* __restrict__ ws) {
  __shared__ float ecol[KCODES];     // column c of emb (4 KB)
  __shared__ int   hist[KCODES];     // LDS histogram (c==0 blocks only)
  __shared__ float sh[16];
  const int p   = blockIdx.x;        // plane: b*64 + c
  const int tid = threadIdx.x;
  const int b = p >> 6, c = p & 63;
  const bool docnt = (c == 0);
  ecol[tid] = emb[(size_t)tid * CH + c];
  if (docnt) hist[tid] = 0;
  __syncthreads();

  const size_t base = (size_t)p * DHWC;
  const float4* zp = (const float4*)(z + base);
  float4* op = (float4*)(out + base);
  const int nbase = b * 16384;
  const float*          hd0 = ws->hd + nbase;
  const float*          hd1 = ws->hd + NTOK + nbase;
  const unsigned short* hk0 = ws->hk + nbase;
  const unsigned short* hk1 = ws->hk + NTOK + nbase;
  float lp = 0.f;
  #pragma unroll
  for (int i = tid; i < 4096; i += 1024) {         // 4 iterations
    float4 v  = zp[i];
    float4 d0 = *(const float4*)(hd0 + 4 * i);
    float4 d1 = *(const float4*)(hd1 + 4 * i);
    ushort4 ka = *(const ushort4*)(hk0 + 4 * i);
    ushort4 kb = *(const ushort4*)(hk1 + 4 * i);
    int w0 = (d0.x < d1.x || (d0.x == d1.x && ka.x < kb.x)) ? ka.x : kb.x;
    int w1 = (d0.y < d1.y || (d0.y == d1.y && ka.y < kb.y)) ? ka.y : kb.y;
    int w2 = (d0.z < d1.z || (d0.z == d1.z && ka.z < kb.z)) ? ka.z : kb.z;
    int w3 = (d0.w < d1.w || (d0.w == d1.w && ka.w < kb.w)) ? ka.w : kb.w;
    float q0 = ecol[w0], q1 = ecol[w1], q2 = ecol[w2], q3 = ecol[w3];
    float e0 = q0 - v.x, e1 = q1 - v.y, e2 = q2 - v.z, e3 = q3 - v.w;
    float4 o; o.x = v.x + e0; o.y = v.y + e1; o.z = v.z + e2; o.w = v.w + e3;
    op[i] = o;
    lp = fmaf(e0, e0, lp); lp = fmaf(e1, e1, lp);
    lp = fmaf(e2, e2, lp); lp = fmaf(e3, e3, lp);
    if (docnt) {
      atomicAdd(&hist[w0], 1);
      atomicAdd(&hist[w1], 1);
      atomicAdd(&hist[w2], 1);
      atomicAdd(&hist[w3], 1);
    }
  }
  #pragma unroll
  for (int off = 32; off > 0; off >>= 1) lp += __shfl_down(lp, off);
  if ((tid & 63) == 0) sh[tid >> 6] = lp;
  __syncthreads();
  if (docnt) {
    int h2 = hist[tid];
    if (h2) atomicAdd(&ws->counts[tid], h2);
  }
  if (tid == 0) {
    float t = 0.f;
    #pragma unroll
    for (int i = 0; i < 16; ++i) t += sh[i];
    atomicAdd(&ws->loss_sum, (double)t);
  }
}

// ---- final: scalars ------------------------------------------------------
__global__ void vq_final(Ws* __restrict__ ws, float* __restrict__ out_scalars) {
  const int tid = threadIdx.x;
  float p = (float)ws->counts[tid] * (1.0f / 65536.0f);
  float term = p * logf(p + 1e-10f);
  __shared__ float sh[1024];
  sh[tid] = term;
  __syncthreads();
  for (int off = 512; off > 0; off >>= 1) {
    if (tid < off) sh[tid] += sh[tid + off];
    __syncthreads();
  }
  if (tid == 0) {
    float perp = expf(-sh[0]);
    double m = ws->loss_sum / (double)OUT_ELEMS;
    float mf = (float)m;
    float loss = mf + 0.25f * mf;
    double sdot = 0.0;
    #pragma unroll
    for (int c = 0; c < CH; ++c) sdot += (double)ws->sum_z[c] * ws->sum_e[c];
    double md = ws->sum_z2 / (double)NTOK + ws->sum_e2 / (double)KCODES
              - 2.0 * sdot / ((double)NTOK * (double)KCODES);
    out_scalars[0] = loss;
    out_scalars[1] = perp;
    out_scalars[2] = (float)md;
  }
}

extern "C" void kernel_launch(void* const* d_in, const int* in_sizes, int n_in,
                              void* d_out, int out_size, void* d_ws, size_t ws_size,
                              hipStream_t stream) {
  const float* z   = (const float*)d_in[0];
  const float* emb = (const float*)d_in[1];
  float* out = (float*)d_out;
  Ws* ws = (Ws*)d_ws;

  hipMemsetAsync(d_ws, 0, offsetof(Ws, e_norm), stream);
  vq_eprep <<<16,   256,  0, stream>>>(emb, ws);
  vq_gemm  <<<512,  256,  0, stream>>>(z, emb, ws);
  vq_writer<<<256,  1024, 0, stream>>>(z, emb, out, ws);
  vq_final <<<1,    1024, 0, stream>>>(ws, out + OUT_ELEMS);
}